// Round 5
// baseline (443.990 us; speedup 1.0000x reference)
//
#include <hip/hip_runtime.h>
#include <hip/hip_fp16.h>

// ---- fp8 e4m3 (OCP) helpers, HW converters on gfx950 ----
__device__ __forceinline__ unsigned char f32_to_fp8(float v) {
  return (unsigned char)(__builtin_amdgcn_cvt_pk_fp8_f32(v, 0.f, 0, false) & 0xff);
}
__device__ __forceinline__ float fp8_to_f32(unsigned char b) {
  return __builtin_amdgcn_cvt_f32_fp8((int)b, 0);
}

// ---------------- degree count (streaming, nt loads) ----------------
__global__ __launch_bounds__(256) void count_deg(const int* __restrict__ dst, int E,
                                                 int* __restrict__ counts) {
  int e = blockIdx.x * 256 + threadIdx.x;
  if (e < E) {
    int d = __builtin_nontemporal_load(&dst[e]);
    atomicAdd(&counts[d], 1);
  }
}

// ---------------- 3-phase exclusive scan ----------------
__device__ __forceinline__ int wave_incl_scan(int v, int lane) {
#pragma unroll
  for (int off = 1; off < 64; off <<= 1) {
    int u = __shfl_up(v, off, 64);
    if (lane >= off) v += u;
  }
  return v;
}

__global__ __launch_bounds__(1024) void scan_partial(const int* __restrict__ counts, int N,
                                                     int* __restrict__ rowptr,
                                                     int* __restrict__ blocksums,
                                                     float* __restrict__ dinv) {
  __shared__ int wsums[16];
  int t = threadIdx.x;
  int i = blockIdx.x * 1024 + t;
  int lane = t & 63, wv = t >> 6;
  int c = (i < N) ? counts[i] : 0;
  int v = wave_incl_scan(c, lane);
  if (lane == 63) wsums[wv] = v;
  __syncthreads();
  int wbase = 0;
#pragma unroll
  for (int w = 0; w < 16; ++w) wbase += (w < wv) ? wsums[w] : 0;
  int incl = wbase + v;
  if (i < N) {
    rowptr[i] = incl - c;
    dinv[i] = rsqrtf((float)(c + 1));  // +1 self loop
  }
  if (t == 1023) blocksums[blockIdx.x] = incl;
}

__global__ __launch_bounds__(1024) void scan_sums(const int* __restrict__ blocksums, int nb,
                                                  int* __restrict__ blockoff) {
  __shared__ int wsums[16];
  int t = threadIdx.x;
  int lane = t & 63, wv = t >> 6;
  int c = (t < nb) ? blocksums[t] : 0;
  int v = wave_incl_scan(c, lane);
  if (lane == 63) wsums[wv] = v;
  __syncthreads();
  int wbase = 0;
#pragma unroll
  for (int w = 0; w < 16; ++w) wbase += (w < wv) ? wsums[w] : 0;
  int incl = wbase + v;
  if (t < nb) blockoff[t] = incl - c;
}

__global__ __launch_bounds__(256) void add_offsets(int* __restrict__ rowptr,
                                                   const int* __restrict__ blockoff, int N, int E) {
  int i = blockIdx.x * 256 + threadIdx.x;
  if (i < N) rowptr[i] += blockoff[i >> 10];
  if (i == 0) rowptr[N] = E;
}

// ---------------- CSR fill, XCD-range-filtered ----------------
// grid = 8 ranges x chunks. Block b: dst-range (b&7) == its XCD (round-robin),
// edge chunk (b>>3). Writes (cursor atomics + colidx) stay in ~850KB/XCD -> L2-local.
__global__ __launch_bounds__(256) void fill_csr(const int* __restrict__ src,
                                                const int* __restrict__ dst, int E, int N,
                                                const int* __restrict__ rowptr,
                                                int* __restrict__ cursor,
                                                int* __restrict__ colidx, int chunks) {
  int range = blockIdx.x & 7;
  int chunk = blockIdx.x >> 3;
  int per = (N + 7) >> 3;
  int lo = range * per, hi = min(N, lo + per);
  int e0 = (int)((long long)chunk * E / chunks);
  int e1 = (int)((long long)(chunk + 1) * E / chunks);
  for (int e = e0 + (int)threadIdx.x; e < e1; e += 256) {
    int d = __builtin_nontemporal_load(&dst[e]);
    if (d >= lo && d < hi) {
      int s = __builtin_nontemporal_load(&src[e]);
      int p = rowptr[d] + atomicAdd(&cursor[d], 1);
      colidx[p] = s;
    }
  }
}

// ---------------- GEMM: gbuf[i][c] = fp8(dinv[i] * sum_k in[i][k]*W[k][c]) ----------------
template <int K, typename Tin>
__global__ __launch_bounds__(256) void gemm_dinv(const Tin* __restrict__ in,
                                                 const float* __restrict__ W,
                                                 const float* __restrict__ dinv,
                                                 unsigned char* __restrict__ out, int N, int tiles) {
  constexpr int K4 = K / 4;
  __shared__ float4 Ws4[64][K4];
  __shared__ float Xs[32][K];
  int t = threadIdx.x;
  for (int j = t; j < 64 * K4; j += 256) {
    int c = j / K4, k4 = j % K4;
    float4 v;
    v.x = W[(4 * k4 + 0) * 64 + c];
    v.y = W[(4 * k4 + 1) * 64 + c];
    v.z = W[(4 * k4 + 2) * 64 + c];
    v.w = W[(4 * k4 + 3) * 64 + c];
    Ws4[c][k4 ^ (c & 7)] = v;
  }
  __syncthreads();
  int c0 = t & 31, rg = t >> 5;
  for (int tile = blockIdx.x; tile < tiles; tile += gridDim.x) {
    int row0 = tile * 32;
    if constexpr (sizeof(Tin) == 4) {
      for (int j = t; j < 32 * K4; j += 256) {
        int r = j / K4, k4 = j % K4;
        int rr = row0 + r;
        float4 v = (rr < N) ? *(const float4*)&in[(size_t)rr * K + 4 * k4]
                            : make_float4(0.f, 0.f, 0.f, 0.f);
        *(float4*)&Xs[r][4 * k4] = v;
      }
    } else {
      for (int j = t; j < 32 * (K / 2); j += 256) {
        int r = j / (K / 2), kk = j % (K / 2);
        int rr = row0 + r;
        float2 v = make_float2(0.f, 0.f);
        if (rr < N) {
          __half2 h = *(const __half2*)&in[(size_t)rr * K + 2 * kk];
          v = __half22float2(h);
        }
        Xs[r][2 * kk] = v.x;
        Xs[r][2 * kk + 1] = v.y;
      }
    }
    __syncthreads();
    float acc[4][2];
#pragma unroll
    for (int r = 0; r < 4; ++r) { acc[r][0] = 0.f; acc[r][1] = 0.f; }
#pragma unroll 4
    for (int k4 = 0; k4 < K4; ++k4) {
      float4 w0 = Ws4[c0][k4 ^ (c0 & 7)];
      float4 w1 = Ws4[c0 + 32][k4 ^ (c0 & 7)];
#pragma unroll
      for (int r = 0; r < 4; ++r) {
        float4 xv = *(const float4*)&Xs[rg * 4 + r][4 * k4];
        acc[r][0] = fmaf(xv.w, w0.w, fmaf(xv.z, w0.z, fmaf(xv.y, w0.y, fmaf(xv.x, w0.x, acc[r][0]))));
        acc[r][1] = fmaf(xv.w, w1.w, fmaf(xv.z, w1.z, fmaf(xv.y, w1.y, fmaf(xv.x, w1.x, acc[r][1]))));
      }
    }
#pragma unroll
    for (int r = 0; r < 4; ++r) {
      int row = row0 + rg * 4 + r;
      if (row < N) {
        float s = dinv[row];
        out[(size_t)row * 64 + c0]      = f32_to_fp8(acc[r][0] * s);
        out[(size_t)row * 64 + c0 + 32] = f32_to_fp8(acc[r][1] * s);
      }
    }
    __syncthreads();
  }
}

// ---------------- aggregation: h[d] = dinv[d]*(g[d] + sum_nb g[s]) + b ----------------
// one wave per contiguous node chunk; lane = feature column; fp8 gathers = 64B/line-exact.
// mode 0: relu -> fp16 ybuf. mode 1: fused mean-pool partials (sorted batch).
__global__ __launch_bounds__(256) void aggregate(const unsigned char* __restrict__ g,
                                                 const int* __restrict__ rowptr,
                                                 const int* __restrict__ colidx,
                                                 const float* __restrict__ dinv,
                                                 const float* __restrict__ bias,
                                                 const int* __restrict__ batch,
                                                 __half* __restrict__ out,
                                                 float* __restrict__ poolsum,
                                                 float* __restrict__ poolcnt,
                                                 int N, int mode) {
  int lane = threadIdx.x & 63;
  int wave = blockIdx.x * 4 + (threadIdx.x >> 6);
  int nwaves = gridDim.x * 4;
  int per = (N + nwaves - 1) / nwaves;
  int n0 = wave * per, n1 = min(N, n0 + per);
  if (n0 >= n1) return;
  float b = bias[lane];
  int cur = mode ? batch[n0] : 0;
  float pacc = 0.f, pcnt = 0.f;
  for (int node = n0; node < n1; ++node) {
    int p0 = rowptr[node], p1 = rowptr[node + 1];
    float a0 = fp8_to_f32(g[(size_t)node * 64 + lane]);  // self (dinv-prescaled)
    float a1 = 0.f, a2 = 0.f, a3 = 0.f;
    float a4 = 0.f, a5 = 0.f, a6 = 0.f, a7 = 0.f;
    for (int base = p0; base < p1; base += 64) {
      int idx = base + lane;
      int nb = (idx < p1) ? colidx[idx] : 0;
      int cnt = min(64, p1 - base);
      int j = 0;
      for (; j + 7 < cnt; j += 8) {  // 8 independent 64B gathers in flight
        int s0 = __shfl(nb, j, 64);
        int s1 = __shfl(nb, j + 1, 64);
        int s2 = __shfl(nb, j + 2, 64);
        int s3 = __shfl(nb, j + 3, 64);
        int s4 = __shfl(nb, j + 4, 64);
        int s5 = __shfl(nb, j + 5, 64);
        int s6 = __shfl(nb, j + 6, 64);
        int s7 = __shfl(nb, j + 7, 64);
        a0 += fp8_to_f32(g[(size_t)s0 * 64 + lane]);
        a1 += fp8_to_f32(g[(size_t)s1 * 64 + lane]);
        a2 += fp8_to_f32(g[(size_t)s2 * 64 + lane]);
        a3 += fp8_to_f32(g[(size_t)s3 * 64 + lane]);
        a4 += fp8_to_f32(g[(size_t)s4 * 64 + lane]);
        a5 += fp8_to_f32(g[(size_t)s5 * 64 + lane]);
        a6 += fp8_to_f32(g[(size_t)s6 * 64 + lane]);
        a7 += fp8_to_f32(g[(size_t)s7 * 64 + lane]);
      }
      for (; j + 3 < cnt; j += 4) {
        int s0 = __shfl(nb, j, 64);
        int s1 = __shfl(nb, j + 1, 64);
        int s2 = __shfl(nb, j + 2, 64);
        int s3 = __shfl(nb, j + 3, 64);
        a0 += fp8_to_f32(g[(size_t)s0 * 64 + lane]);
        a1 += fp8_to_f32(g[(size_t)s1 * 64 + lane]);
        a2 += fp8_to_f32(g[(size_t)s2 * 64 + lane]);
        a3 += fp8_to_f32(g[(size_t)s3 * 64 + lane]);
      }
      for (; j < cnt; ++j) a0 += fp8_to_f32(g[(size_t)__shfl(nb, j, 64) * 64 + lane]);
    }
    float r = dinv[node] * (((a0 + a1) + (a2 + a3)) + ((a4 + a5) + (a6 + a7))) + b;
    if (mode == 0) {
      out[(size_t)node * 64 + lane] = __float2half(fmaxf(r, 0.f));
    } else {
      int bg = batch[node];
      if (bg != cur) {
        atomicAdd(&poolsum[cur * 64 + lane], pacc);
        if (lane == 0) atomicAdd(&poolcnt[cur], pcnt);
        pacc = 0.f; pcnt = 0.f; cur = bg;
      }
      pacc += r; pcnt += 1.f;
    }
  }
  if (mode) {
    atomicAdd(&poolsum[cur * 64 + lane], pacc);
    if (lane == 0) atomicAdd(&poolcnt[cur], pcnt);
  }
}

__global__ __launch_bounds__(256) void finalize(const float* __restrict__ poolsum,
                                                const float* __restrict__ poolcnt,
                                                float* __restrict__ out, int Gn) {
  int i = blockIdx.x * 256 + threadIdx.x;
  if (i < Gn * 64) {
    float c = poolcnt[i >> 6];
    out[i] = poolsum[i] / fmaxf(c, 1.f);
  }
}

extern "C" void kernel_launch(void* const* d_in, const int* in_sizes, int n_in,
                              void* d_out, int out_size, void* d_ws, size_t ws_size,
                              hipStream_t stream) {
  const float* x   = (const float*)d_in[0];
  const int* ei    = (const int*)d_in[1];
  const int* batch = (const int*)d_in[2];
  const float* W1  = (const float*)d_in[3];
  const float* b1  = (const float*)d_in[4];
  const float* W2  = (const float*)d_in[5];
  const float* b2  = (const float*)d_in[6];
  float* out = (float*)d_out;

  int N  = in_sizes[2];
  int E  = in_sizes[1] / 2;
  int Gn = out_size / 64;

  char* ws = (char*)d_ws;
  size_t off = 0;
  auto alloc = [&](size_t bytes) -> void* {
    void* p = ws + off;
    off = (off + bytes + 255) & ~(size_t)255;
    return p;
  };
  int* counts    = (int*)alloc(4ull * N);
  int* cursor    = (int*)alloc(4ull * N);
  float* poolsum = (float*)alloc(4ull * Gn * 64);
  float* poolcnt = (float*)alloc(4ull * Gn);
  size_t zero_bytes = off;  // zero-init region
  int* rowptr    = (int*)alloc(4ull * (N + 1));
  float* dinv    = (float*)alloc(4ull * N);
  int* blocksums = (int*)alloc(4ull * 1024);
  int* blockoff  = (int*)alloc(4ull * 1024);
  int* colidx    = (int*)alloc(4ull * E);
  unsigned char* gbuf = (unsigned char*)alloc(1ull * (size_t)N * 64);
  __half* ybuf   = (__half*)alloc(2ull * (size_t)N * 64);
  (void)ws_size; (void)n_in;

  hipMemsetAsync(d_ws, 0, zero_bytes, stream);

  const int* srcv = ei;
  const int* dstv = ei + E;
  int nb1024 = (N + 1023) / 1024;
  int tiles = (N + 31) / 32;

  // CSR build (compact, range-filtered fill)
  count_deg<<<(E + 255) / 256, 256, 0, stream>>>(dstv, E, counts);
  scan_partial<<<nb1024, 1024, 0, stream>>>(counts, N, rowptr, blocksums, dinv);
  scan_sums<<<1, 1024, 0, stream>>>(blocksums, nb1024, blockoff);
  add_offsets<<<(N + 256) / 256, 256, 0, stream>>>(rowptr, blockoff, N, E);
  fill_csr<<<8 * 256, 256, 0, stream>>>(srcv, dstv, E, N, rowptr, cursor, colidx, 256);

  // layer 1
  gemm_dinv<128, float><<<1536, 256, 0, stream>>>(x, W1, dinv, gbuf, N, tiles);
  aggregate<<<2048, 256, 0, stream>>>(gbuf, rowptr, colidx, dinv, b1, batch, ybuf,
                                      nullptr, nullptr, N, 0);
  // layer 2 (+fused mean-pool partials)
  gemm_dinv<64, __half><<<1536, 256, 0, stream>>>(ybuf, W2, dinv, gbuf, N, tiles);
  aggregate<<<2048, 256, 0, stream>>>(gbuf, rowptr, colidx, dinv, b2, batch, nullptr,
                                      poolsum, poolcnt, N, 1);
  finalize<<<(Gn * 64 + 255) / 256, 256, 0, stream>>>(poolsum, poolcnt, out, Gn);
}